// Round 1
// baseline (849.987 us; speedup 1.0000x reference)
//
#include <hip/hip_runtime.h>

// NSA attention, fp32 end-to-end.
// K1: compress k/v -> ck/cv            (ws)
// K2: cmp attention -> cmp_o (in d_out), blk_mask (ws)
// K3: sel+win flash attention + gated combine -> d_out (reads cmp_o in place)

#define S_LEN 1536
#define HQ    16
#define HKV   2
#define DH    128
#define TC    95          // (1536-32)/16 + 1
#define WIN   512
#define SCALE 0.08838834764831845f   // 1/sqrt(128)

// ---------------------------------------------------------------- kernel 1
__global__ __launch_bounds__(128) void compress_kernel(
    const float* __restrict__ kin, const float* __restrict__ vin,
    const float* __restrict__ Wk,  const float* __restrict__ bk,
    const float* __restrict__ Wv,  const float* __restrict__ bv,
    const float* __restrict__ pek, const float* __restrict__ pev,
    float* __restrict__ ck, float* __restrict__ cv)
{
    const int t0    = blockIdx.x * 5;     // 19 blocks * 5 = 95 = TC
    const int kv    = blockIdx.y;
    const int which = blockIdx.z;         // 0 = k path, 1 = v path
    const float* __restrict__ x  = which ? vin : kin;
    const float* __restrict__ W  = which ? Wv  : Wk;
    const float* __restrict__ bb = which ? bv  : bk;
    const float* __restrict__ pe = which ? pev : pek;
    float* __restrict__ outp     = which ? cv  : ck;
    const int d = threadIdx.x;

    __shared__ float xs[5][128];
    float acc[5] = {0.f, 0.f, 0.f, 0.f, 0.f};

    for (int l = 0; l < 32; ++l) {
        float p = pe[l*DH + d];
        #pragma unroll
        for (int tt = 0; tt < 5; ++tt) {
            int row = (t0 + tt)*16 + l;           // <= 94*16+31 = 1535
            xs[tt][d] = x[(row*HKV + kv)*DH + d] + p;
        }
        __syncthreads();
        const float* wcol = W + l*DH*DH + d;      // W[(l*128+dd)*128 + d]
        for (int dd = 0; dd < 128; ++dd) {
            float w = wcol[dd*DH];
            #pragma unroll
            for (int tt = 0; tt < 5; ++tt) acc[tt] += xs[tt][dd] * w;
        }
        __syncthreads();
    }
    float bias = bb[d];
    #pragma unroll
    for (int tt = 0; tt < 5; ++tt)
        outp[((t0 + tt)*HKV + kv)*DH + d] = acc[tt] + bias;
}

// ---------------------------------------------------------------- kernel 2
__global__ __launch_bounds__(256) void cmp_attn_kernel(
    const float* __restrict__ q, const float* __restrict__ ck,
    const float* __restrict__ cv, float* __restrict__ cmp_o,
    unsigned int* __restrict__ blk_mask)
{
    const int s   = blockIdx.x;
    const int kv  = blockIdx.y;
    const int tid = threadIdx.x;

    __shared__ __align__(16) float qs[8][128];
    __shared__ float lt[8][96];      // logits, then probabilities, per group-head
    __shared__ float score[96];
    __shared__ float pooled[24];

    for (int i = tid; i < 8*128; i += 256) {
        int g = i >> 7, d = i & 127;
        qs[g][d] = q[(size_t)(s*HQ + kv*8 + g)*DH + d];
    }
    __syncthreads();

    const int nv = (s >= 31) ? (((s - 31) >> 4) + 1) : 0;  // # visible cmp blocks

    // logits: 8 heads x 95 blocks
    for (int i = tid; i < 8*TC; i += 256) {
        int g = i / TC, t = i - g*TC;
        const float4* ckr = (const float4*)(ck + (size_t)(t*HKV + kv)*DH);
        const float4* qr  = (const float4*)qs[g];
        float acc = 0.f;
        #pragma unroll 8
        for (int j = 0; j < 32; ++j) {
            float4 a = qr[j], b = ckr[j];
            acc += a.x*b.x + a.y*b.y + a.z*b.z + a.w*b.w;
        }
        lt[g][t] = acc * SCALE;
    }
    __syncthreads();

    // masked softmax per head; 32 lanes per head
    const int g = tid >> 5, lane = tid & 31;
    float m = -3.4e38f;
    for (int t = lane; t < nv; t += 32) m = fmaxf(m, lt[g][t]);
    #pragma unroll
    for (int off = 16; off; off >>= 1) m = fmaxf(m, __shfl_xor(m, off, 32));
    float ssum = 0.f;
    for (int t = lane; t < TC; t += 32) {
        float e = (t < nv) ? __expf(lt[g][t] - m) : 0.f;
        lt[g][t] = e;
        ssum += e;
    }
    #pragma unroll
    for (int off = 16; off; off >>= 1) ssum += __shfl_xor(ssum, off, 32);
    const float inv = 1.f / fmaxf(ssum, 1e-9f);
    for (int t = lane; t < TC; t += 32) lt[g][t] *= inv;
    // (same-wave LDS ordering: each 32-lane group only touches its own row)

    // cmp_o[g][lane*4 .. +3]
    {
        float4 acc = make_float4(0.f, 0.f, 0.f, 0.f);
        for (int t = 0; t < TC; ++t) {
            float p = lt[g][t];
            float4 v4 = *(const float4*)(cv + (size_t)(t*HKV + kv)*DH + lane*4);
            acc.x += p*v4.x; acc.y += p*v4.y; acc.z += p*v4.z; acc.w += p*v4.w;
        }
        *(float4*)(cmp_o + (size_t)(s*HQ + kv*8 + g)*DH + lane*4) = acc;
    }
    __syncthreads();

    // group-summed scores -> avgpool -> stable top-16
    if (tid < TC) {
        float sc = 0.f;
        #pragma unroll
        for (int gg = 0; gg < 8; ++gg) sc += lt[gg][tid];
        score[tid] = sc;
    }
    __syncthreads();
    if (tid < 24) {
        float acc = 0.f, cnt = 0.f;
        #pragma unroll
        for (int j = 0; j < 5; ++j) {
            int w = tid*4 + j;                      // stride 4, kernel 5, pad 0
            if (w < TC) { acc += score[w]; cnt += 1.f; }
        }
        pooled[tid] = acc / cnt;                    // count_include_pad (P=0)
    }
    __syncthreads();
    bool sel = false;
    if (tid < 24) {
        float pvv = pooled[tid];
        int rank = 0;
        #pragma unroll
        for (int j = 0; j < 24; ++j) {
            float pj = pooled[j];
            rank += ((pj > pvv) || (pj == pvv && j < tid)) ? 1 : 0;
        }
        sel = rank < 16;   // == lax.top_k stable tie-break (lower index wins)
    }
    unsigned long long b = __ballot(sel);
    if (tid == 0) blk_mask[kv*S_LEN + s] = (unsigned int)(b & 0xFFFFFFull);
}

// ---------------------------------------------------------------- kernel 3
__global__ __launch_bounds__(256) void main_attn_kernel(
    const float* __restrict__ q, const float* __restrict__ kg,
    const float* __restrict__ vg, const float* cmp_o,   // aliases `out`!
    const unsigned int* __restrict__ blk_mask,
    const float* __restrict__ Wg, const float* __restrict__ bg,
    float* out)
{
    const int s   = blockIdx.x;
    const int kv  = blockIdx.y;
    const int tid = threadIdx.x;
    const int h8  = tid >> 5;     // head within group, 32 threads per head
    const int c   = tid & 31;     // covers d = 4c .. 4c+3

    __shared__ __align__(16) float qs[8][128];
    __shared__ __align__(16) float kvt[64][132];  // +4 pad: break bank stride
    __shared__ float ps[8][64];
    __shared__ float pw[8][64];

    for (int i = tid; i < 8*128; i += 256) {
        int hh = i >> 7, d = i & 127;
        qs[hh][d] = q[(size_t)(s*HQ + kv*8 + hh)*DH + d];
    }
    __syncthreads();

    const unsigned int mask = blk_mask[kv*S_LEN + s];
    const int nkb = (s >> 6) + 1;
    const int wlo = s - WIN + 1;   // window: key >= wlo && key <= s

    float m_s = -3.4e38f, l_s = 0.f;
    float m_w = -3.4e38f, l_w = 0.f;
    float4 O_s = make_float4(0.f, 0.f, 0.f, 0.f);
    float4 O_w = make_float4(0.f, 0.f, 0.f, 0.f);

    for (int kb = 0; kb < nkb; ++kb) {
        const bool selected = (mask >> kb) & 1u;
        const bool winb = (kb*64 + 63) >= wlo;
        if (!(selected || winb)) continue;

        // stage K tile
        for (int i = tid; i < 64*32; i += 256) {
            int r = i >> 5, cc = i & 31;
            int key = kb*64 + r;
            *(float4*)&kvt[r][cc*4] =
                *(const float4*)(kg + (size_t)(key*HKV + kv)*DH + cc*4);
        }
        __syncthreads();

        // logits for keys r=c and r=c+32 of head h8
        float l0 = 0.f, l1 = 0.f;
        {
            const float4* qr = (const float4*)qs[h8];
            const float4* k0 = (const float4*)&kvt[c][0];
            const float4* k1 = (const float4*)&kvt[c + 32][0];
            #pragma unroll 8
            for (int j = 0; j < 32; ++j) {
                float4 a = qr[j];
                float4 b0 = k0[j];
                float4 b1 = k1[j];
                l0 += a.x*b0.x + a.y*b0.y + a.z*b0.z + a.w*b0.w;
                l1 += a.x*b1.x + a.y*b1.y + a.z*b1.z + a.w*b1.w;
            }
        }
        l0 *= SCALE; l1 *= SCALE;
        const int key0 = kb*64 + c, key1 = key0 + 32;
        const bool s0 = selected && (key0 <= s);
        const bool s1 = selected && (key1 <= s);
        const bool w0 = (key0 <= s) && (key0 >= wlo);
        const bool w1 = (key1 <= s) && (key1 >= wlo);

        // --- selected-branch online softmax ---
        {
            float bm = fmaxf(s0 ? l0 : -3.4e38f, s1 ? l1 : -3.4e38f);
            #pragma unroll
            for (int off = 16; off; off >>= 1) bm = fmaxf(bm, __shfl_xor(bm, off, 32));
            float nm = fmaxf(m_s, bm);
            float alpha = (nm <= -3.4e38f) ? 1.f : __expf(m_s - nm);
            float p0 = s0 ? __expf(l0 - nm) : 0.f;
            float p1 = s1 ? __expf(l1 - nm) : 0.f;
            ps[h8][c] = p0; ps[h8][c + 32] = p1;
            float bs = p0 + p1;
            #pragma unroll
            for (int off = 16; off; off >>= 1) bs += __shfl_xor(bs, off, 32);
            l_s = l_s * alpha + bs;
            m_s = nm;
            O_s.x *= alpha; O_s.y *= alpha; O_s.z *= alpha; O_s.w *= alpha;
        }
        // --- window-branch online softmax ---
        {
            float bm = fmaxf(w0 ? l0 : -3.4e38f, w1 ? l1 : -3.4e38f);
            #pragma unroll
            for (int off = 16; off; off >>= 1) bm = fmaxf(bm, __shfl_xor(bm, off, 32));
            float nm = fmaxf(m_w, bm);
            float alpha = (nm <= -3.4e38f) ? 1.f : __expf(m_w - nm);
            float p0 = w0 ? __expf(l0 - nm) : 0.f;
            float p1 = w1 ? __expf(l1 - nm) : 0.f;
            pw[h8][c] = p0; pw[h8][c + 32] = p1;
            float bs = p0 + p1;
            #pragma unroll
            for (int off = 16; off; off >>= 1) bs += __shfl_xor(bs, off, 32);
            l_w = l_w * alpha + bs;
            m_w = nm;
            O_w.x *= alpha; O_w.y *= alpha; O_w.z *= alpha; O_w.w *= alpha;
        }

        __syncthreads();
        // stage V tile (reuse kvt)
        for (int i = tid; i < 64*32; i += 256) {
            int r = i >> 5, cc = i & 31;
            int key = kb*64 + r;
            *(float4*)&kvt[r][cc*4] =
                *(const float4*)(vg + (size_t)(key*HKV + kv)*DH + cc*4);
        }
        __syncthreads();

        // PV for both branches
        for (int r = 0; r < 64; ++r) {
            float4 v4 = *(const float4*)&kvt[r][c*4];
            float a_s = ps[h8][r];
            float a_w = pw[h8][r];
            O_s.x += a_s*v4.x; O_s.y += a_s*v4.y; O_s.z += a_s*v4.z; O_s.w += a_s*v4.w;
            O_w.x += a_w*v4.x; O_w.y += a_w*v4.y; O_w.z += a_w*v4.z; O_w.w += a_w*v4.w;
        }
        __syncthreads();
    }

    const float inv_s = 1.f / fmaxf(l_s, 1e-9f);
    const float inv_w = 1.f / fmaxf(l_w, 1e-9f);

    // gate = sigmoid(q . Wg + bg), reduced across the 32 threads of the head
    float g0 = 0.f, g1 = 0.f, g2 = 0.f;
    {
        const float4* qr = (const float4*)qs[h8];
        float4 a = qr[c];
        float qv[4] = {a.x, a.y, a.z, a.w};
        #pragma unroll
        for (int j = 0; j < 4; ++j) {
            int d = c*4 + j;
            g0 += qv[j] * Wg[d*3 + 0];
            g1 += qv[j] * Wg[d*3 + 1];
            g2 += qv[j] * Wg[d*3 + 2];
        }
    }
    #pragma unroll
    for (int off = 16; off; off >>= 1) {
        g0 += __shfl_xor(g0, off, 32);
        g1 += __shfl_xor(g1, off, 32);
        g2 += __shfl_xor(g2, off, 32);
    }
    g0 = 1.f / (1.f + __expf(-(g0 + bg[0])));
    g1 = 1.f / (1.f + __expf(-(g1 + bg[1])));
    g2 = 1.f / (1.f + __expf(-(g2 + bg[2])));

    const size_t oidx = (size_t)(s*HQ + kv*8 + h8)*DH + c*4;
    float4 cm = *(const float4*)(cmp_o + oidx);   // read BEFORE overwrite
    float4 o;
    o.x = g0*O_s.x*inv_s + g1*O_w.x*inv_w + g2*cm.x;
    o.y = g0*O_s.y*inv_s + g1*O_w.y*inv_w + g2*cm.y;
    o.z = g0*O_s.z*inv_s + g1*O_w.z*inv_w + g2*cm.z;
    o.w = g0*O_s.w*inv_s + g1*O_w.w*inv_w + g2*cm.w;
    *(float4*)(out + oidx) = o;
}

// ---------------------------------------------------------------- launcher
extern "C" void kernel_launch(void* const* d_in, const int* in_sizes, int n_in,
                              void* d_out, int out_size, void* d_ws, size_t ws_size,
                              hipStream_t stream) {
    const float* q   = (const float*)d_in[0];
    const float* k   = (const float*)d_in[1];
    const float* v   = (const float*)d_in[2];
    const float* Wk  = (const float*)d_in[3];
    const float* bk  = (const float*)d_in[4];
    const float* Wv  = (const float*)d_in[5];
    const float* bv  = (const float*)d_in[6];
    const float* pek = (const float*)d_in[7];
    const float* pev = (const float*)d_in[8];
    const float* Wg  = (const float*)d_in[9];
    const float* bg  = (const float*)d_in[10];
    float* out = (float*)d_out;

    char* ws = (char*)d_ws;
    float* ck = (float*)ws;                          //  95*2*128 f = 97,280 B
    float* cv = (float*)(ws + 98304);                //  97,280 B
    unsigned int* blk_mask = (unsigned int*)(ws + 196608); // 2*1536*4 = 12,288 B
    float* cmp_o = out;   // stage cmp_o in d_out; kernel 3 reads it in place

    compress_kernel<<<dim3(19, HKV, 2), 128, 0, stream>>>(
        k, v, Wk, bk, Wv, bv, pek, pev, ck, cv);
    cmp_attn_kernel<<<dim3(S_LEN, HKV), 256, 0, stream>>>(
        q, ck, cv, cmp_o, blk_mask);
    main_attn_kernel<<<dim3(S_LEN, HKV), 256, 0, stream>>>(
        q, k, v, cmp_o, blk_mask, Wg, bg, out);
}

// Round 2
// 559.353 us; speedup vs baseline: 1.5196x; 1.5196x over previous
//
#include <hip/hip_runtime.h>

// NSA attention. K1: compress (fp32). K2: cmp attention + topk (fp32, as R1).
// K3: query-tiled MFMA flash attention (f16 in / f32 accum) + gated combine.

#define S_LEN 1536
#define HQ    16
#define HKV   2
#define DH    128
#define TC    95
#define WIN   512
#define TQ    16
#define SCALE 0.08838834764831845f   // 1/sqrt(128)

typedef _Float16 f16;
typedef f16   f16x8 __attribute__((ext_vector_type(8)));
typedef float f32x4 __attribute__((ext_vector_type(4)));

__device__ inline f16x8 cvt8(float4 A, float4 B) {
    f16x8 h;
    h[0]=(f16)A.x; h[1]=(f16)A.y; h[2]=(f16)A.z; h[3]=(f16)A.w;
    h[4]=(f16)B.x; h[5]=(f16)B.y; h[6]=(f16)B.z; h[7]=(f16)B.w;
    return h;
}

// ---------------------------------------------------------------- kernel 1
__global__ __launch_bounds__(256) void compress_kernel(
    const float* __restrict__ kin, const float* __restrict__ vin,
    const float* __restrict__ Wk,  const float* __restrict__ bk,
    const float* __restrict__ Wv,  const float* __restrict__ bv,
    const float* __restrict__ pek, const float* __restrict__ pev,
    float* __restrict__ ck, float* __restrict__ cv)
{
    const int t0    = blockIdx.x * 5;     // 19 blocks * 5 = 95 = TC
    const int kv    = blockIdx.y;
    const int which = blockIdx.z;
    const float* __restrict__ x  = which ? vin : kin;
    const float* __restrict__ W  = which ? Wv  : Wk;
    const float* __restrict__ bb = which ? bv  : bk;
    const float* __restrict__ pe = which ? pev : pek;
    float* __restrict__ outp     = which ? cv  : ck;
    const int tid = threadIdx.x;
    const int hh  = tid >> 7;             // l-half: 0 -> l 0..15, 1 -> l 16..31
    const int d   = tid & 127;

    __shared__ float xs[2][5][128];
    __shared__ float racc1[5][128];
    float acc[5] = {0.f, 0.f, 0.f, 0.f, 0.f};

    for (int il = 0; il < 16; ++il) {
        int l = hh*16 + il;
        float p = pe[l*DH + d];
        #pragma unroll
        for (int tt = 0; tt < 5; ++tt) {
            int row = (t0 + tt)*16 + l;
            xs[hh][tt][d] = x[(row*HKV + kv)*DH + d] + p;
        }
        __syncthreads();
        const float* wcol = W + l*DH*DH + d;
        #pragma unroll 4
        for (int dd = 0; dd < 128; ++dd) {
            float wv = wcol[dd*DH];
            #pragma unroll
            for (int tt = 0; tt < 5; ++tt) acc[tt] += xs[hh][tt][dd] * wv;
        }
        __syncthreads();
    }
    if (hh == 1) {
        #pragma unroll
        for (int tt = 0; tt < 5; ++tt) racc1[tt][d] = acc[tt];
    }
    __syncthreads();
    if (hh == 0) {
        float bias = bb[d];
        #pragma unroll
        for (int tt = 0; tt < 5; ++tt)
            outp[((t0 + tt)*HKV + kv)*DH + d] = acc[tt] + racc1[tt][d] + bias;
    }
}

// ---------------------------------------------------------------- kernel 2
__global__ __launch_bounds__(256) void cmp_attn_kernel(
    const float* __restrict__ q, const float* __restrict__ ck,
    const float* __restrict__ cv, float* __restrict__ cmp_o,
    unsigned int* __restrict__ blk_mask)
{
    const int s   = blockIdx.x;
    const int kv  = blockIdx.y;
    const int tid = threadIdx.x;

    __shared__ __align__(16) float qs[8][128];
    __shared__ float lt[8][96];
    __shared__ float score[96];
    __shared__ float pooled[24];

    for (int i = tid; i < 8*128; i += 256) {
        int g = i >> 7, d = i & 127;
        qs[g][d] = q[(size_t)(s*HQ + kv*8 + g)*DH + d];
    }
    __syncthreads();

    const int nv = (s >= 31) ? (((s - 31) >> 4) + 1) : 0;

    for (int i = tid; i < 8*TC; i += 256) {
        int g = i / TC, t = i - g*TC;
        const float4* ckr = (const float4*)(ck + (size_t)(t*HKV + kv)*DH);
        const float4* qr  = (const float4*)qs[g];
        float acc = 0.f;
        #pragma unroll 8
        for (int j = 0; j < 32; ++j) {
            float4 a = qr[j], b = ckr[j];
            acc += a.x*b.x + a.y*b.y + a.z*b.z + a.w*b.w;
        }
        lt[g][t] = acc * SCALE;
    }
    __syncthreads();

    const int g = tid >> 5, lane = tid & 31;
    float m = -3.4e38f;
    for (int t = lane; t < nv; t += 32) m = fmaxf(m, lt[g][t]);
    #pragma unroll
    for (int off = 16; off; off >>= 1) m = fmaxf(m, __shfl_xor(m, off, 32));
    float ssum = 0.f;
    for (int t = lane; t < TC; t += 32) {
        float e = (t < nv) ? __expf(lt[g][t] - m) : 0.f;
        lt[g][t] = e;
        ssum += e;
    }
    #pragma unroll
    for (int off = 16; off; off >>= 1) ssum += __shfl_xor(ssum, off, 32);
    const float inv = 1.f / fmaxf(ssum, 1e-9f);
    for (int t = lane; t < TC; t += 32) lt[g][t] *= inv;

    {
        float4 acc = make_float4(0.f, 0.f, 0.f, 0.f);
        for (int t = 0; t < TC; ++t) {
            float p = lt[g][t];
            float4 v4 = *(const float4*)(cv + (size_t)(t*HKV + kv)*DH + lane*4);
            acc.x += p*v4.x; acc.y += p*v4.y; acc.z += p*v4.z; acc.w += p*v4.w;
        }
        *(float4*)(cmp_o + (size_t)(s*HQ + kv*8 + g)*DH + lane*4) = acc;
    }
    __syncthreads();

    if (tid < TC) {
        float sc = 0.f;
        #pragma unroll
        for (int gg = 0; gg < 8; ++gg) sc += lt[gg][tid];
        score[tid] = sc;
    }
    __syncthreads();
    if (tid < 24) {
        float acc = 0.f, cnt = 0.f;
        #pragma unroll
        for (int j = 0; j < 5; ++j) {
            int w = tid*4 + j;
            if (w < TC) { acc += score[w]; cnt += 1.f; }
        }
        pooled[tid] = acc / cnt;
    }
    __syncthreads();
    bool sel = false;
    if (tid < 24) {
        float pvv = pooled[tid];
        int rank = 0;
        #pragma unroll
        for (int j = 0; j < 24; ++j) {
            float pj = pooled[j];
            rank += ((pj > pvv) || (pj == pvv && j < tid)) ? 1 : 0;
        }
        sel = rank < 16;
    }
    unsigned long long b = __ballot(sel);
    if (tid == 0) blk_mask[kv*S_LEN + s] = (unsigned int)(b & 0xFFFFFFull);
}

// ---------------------------------------------------------------- kernel 3
// Query-tiled MFMA flash attention. Block: (q-tile of 16, kv, head-half).
// Wave w = head (z*4+w); computes 16 queries x all keys of each 64-key tile.
__global__ __launch_bounds__(256, 2) void main_attn_mfma(
    const float* __restrict__ q, const float* __restrict__ kg,
    const float* __restrict__ vg, const float* cmp_o,   // aliases out!
    const unsigned int* __restrict__ blk_mask,
    const float* __restrict__ Wg, const float* __restrict__ bg,
    float* out)
{
    const int t0   = blockIdx.x * TQ;
    const int kv   = blockIdx.y;
    const int z    = blockIdx.z;          // head half (0: heads 0-3, 1: 4-7)
    const int tid  = threadIdx.x;
    const int w    = tid >> 6;
    const int lane = tid & 63;
    const int quad = lane >> 4;
    const int l4   = lane & 15;
    const int head = z*4 + w;             // head within kv group (0..7)

    // LDS: K [64][136] f16, V^T [128][72] f16, P per-wave [16][72] f16
    __shared__ __align__(16) f16 Klds[64*136];   // 17408 B
    __shared__ __align__(16) f16 Vt[128*72];     // 18432 B
    __shared__ __align__(16) f16 Plds[4][16*72]; //  9216 B

    // Q A-frags in registers: A[m=l4][k=quad*8+j], 4 k-steps of 32
    f16x8 aq[4];
    {
        const float* qrow = q + ((size_t)(t0 + l4)*HQ + kv*8 + head)*DH;
        #pragma unroll
        for (int ks = 0; ks < 4; ++ks) {
            float4 A = *(const float4*)(qrow + ks*32 + quad*8);
            float4 B = *(const float4*)(qrow + ks*32 + quad*8 + 4);
            aq[ks] = cvt8(A, B);
        }
    }

    int srow[4]; unsigned selm[4];
    #pragma unroll
    for (int r = 0; r < 4; ++r) {
        srow[r] = t0 + quad*4 + r;
        selm[r] = blk_mask[kv*S_LEN + srow[r]];
    }
    unsigned um = 0;
    for (int i = 0; i < TQ; ++i) um |= blk_mask[kv*S_LEN + t0 + i];

    f32x4 o_s[8], o_w[8];
    #pragma unroll
    for (int nf = 0; nf < 8; ++nf) {
        o_s[nf] = (f32x4){0.f,0.f,0.f,0.f};
        o_w[nf] = (f32x4){0.f,0.f,0.f,0.f};
    }
    float m_s[4], l_s[4], m_w[4], l_w[4];
    #pragma unroll
    for (int r = 0; r < 4; ++r) { m_s[r]=-1e30f; l_s[r]=0.f; m_w[r]=-1e30f; l_w[r]=0.f; }

    const int nkb = ((t0 + TQ - 1) >> 6) + 1;
    const int wlo_tile = t0 - WIN + 1;    // window lower bound for smallest query

    for (int kb = 0; kb < nkb; ++kb) {
        const bool any_sel = (um >> kb) & 1u;
        const bool any_win = (kb*64 + 63) >= wlo_tile;
        if (!(any_sel || any_win)) continue;   // block-uniform

        __syncthreads();
        // ---- stage K tile: [64 keys][128 dims] -> f16, row stride 136
        #pragma unroll
        for (int i = 0; i < 4; ++i) {
            int idx = i*256 + tid;             // 1024 chunks of 8 dims
            int key = idx >> 4, cg = idx & 15;
            const float* src = kg + (((size_t)(kb*64 + key)*HKV + kv))*DH + cg*8;
            float4 A = *(const float4*)src, B = *(const float4*)(src + 4);
            *(f16x8*)&Klds[key*136 + cg*8] = cvt8(A, B);
        }
        // ---- stage V^T tile: Vt[dim][key], row stride 72
        #pragma unroll
        for (int i = 0; i < 4; ++i) {
            int idx = i*256 + tid;             // 1024 = 128 dims x 8 key-groups
            int d = idx & 127, kg8 = idx >> 7;
            f16x8 h;
            #pragma unroll
            for (int j = 0; j < 8; ++j)
                h[j] = (f16)vg[(((size_t)(kb*64 + kg8*8 + j)*HKV + kv))*DH + d];
            *(f16x8*)&Vt[d*72 + kg8*8] = h;
        }
        __syncthreads();

        // ---- S = Q K^T  (C layout: row=quad*4+r -> query, col=nt*16+l4 -> key)
        f32x4 sc[4];
        #pragma unroll
        for (int nt = 0; nt < 4; ++nt) {
            sc[nt] = (f32x4){0.f,0.f,0.f,0.f};
            #pragma unroll
            for (int ks = 0; ks < 4; ++ks) {
                f16x8 bk = *(const f16x8*)&Klds[(nt*16 + l4)*136 + ks*32 + quad*8];
                sc[nt] = __builtin_amdgcn_mfma_f32_16x16x32_f16(aq[ks], bk, sc[nt], 0, 0, 0);
            }
        }

        const int keyb = kb*64;
        // ================= branch SEL =================
        {
            float rmax[4] = {-1e30f,-1e30f,-1e30f,-1e30f};
            #pragma unroll
            for (int nt = 0; nt < 4; ++nt) {
                int key = keyb + nt*16 + l4;
                #pragma unroll
                for (int r = 0; r < 4; ++r) {
                    bool ok = (key <= srow[r]) && ((selm[r] >> kb) & 1u);
                    rmax[r] = fmaxf(rmax[r], ok ? sc[nt][r]*SCALE : -1e30f);
                }
            }
            float alpha[4];
            #pragma unroll
            for (int r = 0; r < 4; ++r) {
                #pragma unroll
                for (int off = 1; off < 16; off <<= 1)
                    rmax[r] = fmaxf(rmax[r], __shfl_xor(rmax[r], off));
                float nm = fmaxf(m_s[r], rmax[r]);
                alpha[r] = __expf(m_s[r] - nm);
                m_s[r] = nm;
            }
            float rs[4] = {0.f,0.f,0.f,0.f};
            #pragma unroll
            for (int nt = 0; nt < 4; ++nt) {
                int key = keyb + nt*16 + l4;
                #pragma unroll
                for (int r = 0; r < 4; ++r) {
                    bool ok = (key <= srow[r]) && ((selm[r] >> kb) & 1u);
                    float p = ok ? __expf(sc[nt][r]*SCALE - m_s[r]) : 0.f;
                    rs[r] += p;
                    Plds[w][(quad*4 + r)*72 + nt*16 + l4] = (f16)p;
                }
            }
            #pragma unroll
            for (int r = 0; r < 4; ++r) {
                #pragma unroll
                for (int off = 1; off < 16; off <<= 1) rs[r] += __shfl_xor(rs[r], off);
                l_s[r] = l_s[r]*alpha[r] + rs[r];
            }
            #pragma unroll
            for (int nf = 0; nf < 8; ++nf) {
                #pragma unroll
                for (int r = 0; r < 4; ++r) o_s[nf][r] *= alpha[r];
            }
            #pragma unroll
            for (int ks2 = 0; ks2 < 2; ++ks2) {
                f16x8 ap = *(const f16x8*)&Plds[w][l4*72 + ks2*32 + quad*8];
                #pragma unroll
                for (int nf = 0; nf < 8; ++nf) {
                    f16x8 bv = *(const f16x8*)&Vt[(nf*16 + l4)*72 + ks2*32 + quad*8];
                    o_s[nf] = __builtin_amdgcn_mfma_f32_16x16x32_f16(ap, bv, o_s[nf], 0, 0, 0);
                }
            }
        }
        // ================= branch WIN =================
        {
            float rmax[4] = {-1e30f,-1e30f,-1e30f,-1e30f};
            #pragma unroll
            for (int nt = 0; nt < 4; ++nt) {
                int key = keyb + nt*16 + l4;
                #pragma unroll
                for (int r = 0; r < 4; ++r) {
                    bool ok = (key <= srow[r]) && (key > srow[r] - WIN);
                    rmax[r] = fmaxf(rmax[r], ok ? sc[nt][r]*SCALE : -1e30f);
                }
            }
            float alpha[4];
            #pragma unroll
            for (int r = 0; r < 4; ++r) {
                #pragma unroll
                for (int off = 1; off < 16; off <<= 1)
                    rmax[r] = fmaxf(rmax[r], __shfl_xor(rmax[r], off));
                float nm = fmaxf(m_w[r], rmax[r]);
                alpha[r] = __expf(m_w[r] - nm);
                m_w[r] = nm;
            }
            float rs[4] = {0.f,0.f,0.f,0.f};
            #pragma unroll
            for (int nt = 0; nt < 4; ++nt) {
                int key = keyb + nt*16 + l4;
                #pragma unroll
                for (int r = 0; r < 4; ++r) {
                    bool ok = (key <= srow[r]) && (key > srow[r] - WIN);
                    float p = ok ? __expf(sc[nt][r]*SCALE - m_w[r]) : 0.f;
                    rs[r] += p;
                    Plds[w][(quad*4 + r)*72 + nt*16 + l4] = (f16)p;
                }
            }
            #pragma unroll
            for (int r = 0; r < 4; ++r) {
                #pragma unroll
                for (int off = 1; off < 16; off <<= 1) rs[r] += __shfl_xor(rs[r], off);
                l_w[r] = l_w[r]*alpha[r] + rs[r];
            }
            #pragma unroll
            for (int nf = 0; nf < 8; ++nf) {
                #pragma unroll
                for (int r = 0; r < 4; ++r) o_w[nf][r] *= alpha[r];
            }
            #pragma unroll
            for (int ks2 = 0; ks2 < 2; ++ks2) {
                f16x8 ap = *(const f16x8*)&Plds[w][l4*72 + ks2*32 + quad*8];
                #pragma unroll
                for (int nf = 0; nf < 8; ++nf) {
                    f16x8 bv = *(const f16x8*)&Vt[(nf*16 + l4)*72 + ks2*32 + quad*8];
                    o_w[nf] = __builtin_amdgcn_mfma_f32_16x16x32_f16(ap, bv, o_w[nf], 0, 0, 0);
                }
            }
        }
    }

    // ---- epilogue: gates + combine + write
    float inv_s[4], inv_w[4];
    #pragma unroll
    for (int r = 0; r < 4; ++r) {
        inv_s[r] = 1.f / fmaxf(l_s[r], 1e-9f);
        inv_w[r] = 1.f / fmaxf(l_w[r], 1e-9f);
    }
    float gt[4][3];
    #pragma unroll
    for (int r = 0; r < 4; ++r) {
        float p0 = 0.f, p1 = 0.f, p2 = 0.f;
        const float* qrow = q + ((size_t)srow[r]*HQ + kv*8 + head)*DH + l4*8;
        #pragma unroll
        for (int j = 0; j < 8; ++j) {
            float qv = qrow[j];
            int d = l4*8 + j;
            p0 += qv * Wg[d*3 + 0];
            p1 += qv * Wg[d*3 + 1];
            p2 += qv * Wg[d*3 + 2];
        }
        #pragma unroll
        for (int off = 1; off < 16; off <<= 1) {
            p0 += __shfl_xor(p0, off);
            p1 += __shfl_xor(p1, off);
            p2 += __shfl_xor(p2, off);
        }
        gt[r][0] = 1.f/(1.f + __expf(-(p0 + bg[0])));
        gt[r][1] = 1.f/(1.f + __expf(-(p1 + bg[1])));
        gt[r][2] = 1.f/(1.f + __expf(-(p2 + bg[2])));
    }
    #pragma unroll
    for (int nf = 0; nf < 8; ++nf) {
        int d = nf*16 + l4;
        #pragma unroll
        for (int r = 0; r < 4; ++r) {
            size_t oi = ((size_t)srow[r]*HQ + kv*8 + head)*DH + d;
            float cm = cmp_o[oi];                 // read before overwrite
            out[oi] = gt[r][0]*o_s[nf][r]*inv_s[r]
                    + gt[r][1]*o_w[nf][r]*inv_w[r]
                    + gt[r][2]*cm;
        }
    }
}

// ---------------------------------------------------------------- launcher
extern "C" void kernel_launch(void* const* d_in, const int* in_sizes, int n_in,
                              void* d_out, int out_size, void* d_ws, size_t ws_size,
                              hipStream_t stream) {
    const float* q   = (const float*)d_in[0];
    const float* k   = (const float*)d_in[1];
    const float* v   = (const float*)d_in[2];
    const float* Wk  = (const float*)d_in[3];
    const float* bk  = (const float*)d_in[4];
    const float* Wv  = (const float*)d_in[5];
    const float* bv  = (const float*)d_in[6];
    const float* pek = (const float*)d_in[7];
    const float* pev = (const float*)d_in[8];
    const float* Wg  = (const float*)d_in[9];
    const float* bg  = (const float*)d_in[10];
    float* out = (float*)d_out;

    char* ws = (char*)d_ws;
    float* ck = (float*)ws;
    float* cv = (float*)(ws + 98304);
    unsigned int* blk_mask = (unsigned int*)(ws + 196608);
    float* cmp_o = out;

    compress_kernel<<<dim3(19, HKV, 2), 256, 0, stream>>>(
        k, v, Wk, bk, Wv, bv, pek, pev, ck, cv);
    cmp_attn_kernel<<<dim3(S_LEN, HKV), 256, 0, stream>>>(
        q, ck, cv, cmp_o, blk_mask);
    main_attn_mfma<<<dim3(S_LEN/TQ, HKV, 2), 256, 0, stream>>>(
        q, k, v, cmp_o, blk_mask, Wg, bg, out);
}

// Round 3
// 440.927 us; speedup vs baseline: 1.9277x; 1.2686x over previous
//
#include <hip/hip_runtime.h>

// NSA attention. K0: init ck/cv with bias. K1: K-split compress (fp32, atomics).
// K2: cmp attention + topk (fp32). K3: query-tiled MFMA flash attention.

#define S_LEN 1536
#define HQ    16
#define HKV   2
#define DH    128
#define TC    95
#define WIN   512
#define TQ    16
#define SCALE 0.08838834764831845f   // 1/sqrt(128)

typedef _Float16 f16;
typedef f16   f16x8 __attribute__((ext_vector_type(8)));
typedef float f32x4 __attribute__((ext_vector_type(4)));

__device__ inline f16x8 cvt8(float4 A, float4 B) {
    f16x8 h;
    h[0]=(f16)A.x; h[1]=(f16)A.y; h[2]=(f16)A.z; h[3]=(f16)A.w;
    h[4]=(f16)B.x; h[5]=(f16)B.y; h[6]=(f16)B.z; h[7]=(f16)B.w;
    return h;
}

// ---------------------------------------------------------------- kernel 0
// ck/cv <- bias broadcast (atomic accumulate target)
__global__ __launch_bounds__(256) void compress_init_kernel(
    const float* __restrict__ bk, const float* __restrict__ bv,
    float* __restrict__ ck, float* __restrict__ cv)
{
    int i = blockIdx.x * 256 + threadIdx.x;       // 190 blocks * 256 = 48640
    int which = i >= TC*HKV*DH;
    int j = i - which*(TC*HKV*DH);
    int d = j & 127;
    (which ? cv : ck)[j] = (which ? bv : bk)[d];
}

// ---------------------------------------------------------------- kernel 1
// K-split: each block does 4 of the 32 l-positions, atomicAdd partials.
__global__ __launch_bounds__(256) void compress_partial_kernel(
    const float* __restrict__ kin, const float* __restrict__ vin,
    const float* __restrict__ Wk,  const float* __restrict__ Wv,
    const float* __restrict__ pek, const float* __restrict__ pev,
    float* __restrict__ ck, float* __restrict__ cv)
{
    const int t0    = blockIdx.x * 5;     // 19 blocks * 5 = 95 = TC
    const int kv    = blockIdx.y >> 1;
    const int which = blockIdx.y & 1;
    const int kc    = blockIdx.z;         // l-chunk: l in [kc*4, kc*4+4)
    const float* __restrict__ x  = which ? vin : kin;
    const float* __restrict__ W  = which ? Wv  : Wk;
    const float* __restrict__ pe = which ? pev : pek;
    float* __restrict__ outp     = which ? cv  : ck;
    const int tid = threadIdx.x;
    const int hh  = tid >> 7;             // half: 2 l's each
    const int d   = tid & 127;

    __shared__ float xs[2][5][128];
    __shared__ float racc[5][128];
    float acc[5] = {0.f, 0.f, 0.f, 0.f, 0.f};

    #pragma unroll
    for (int il = 0; il < 2; ++il) {
        const int l = kc*4 + hh*2 + il;
        float p = pe[l*DH + d];
        #pragma unroll
        for (int tt = 0; tt < 5; ++tt) {
            int row = (t0 + tt)*16 + l;
            xs[hh][tt][d] = x[(row*HKV + kv)*DH + d] + p;
        }
        __syncthreads();
        const float* wcol = W + l*DH*DH + d;
        #pragma unroll 4
        for (int dd = 0; dd < 128; ++dd) {
            float wv = wcol[dd*DH];
            #pragma unroll
            for (int tt = 0; tt < 5; ++tt) acc[tt] += xs[hh][tt][dd] * wv;
        }
        __syncthreads();
    }
    if (hh == 1) {
        #pragma unroll
        for (int tt = 0; tt < 5; ++tt) racc[tt][d] = acc[tt];
    }
    __syncthreads();
    if (hh == 0) {
        #pragma unroll
        for (int tt = 0; tt < 5; ++tt)
            atomicAdd(&outp[((t0 + tt)*HKV + kv)*DH + d], acc[tt] + racc[tt][d]);
    }
}

// ---------------------------------------------------------------- kernel 2
__global__ __launch_bounds__(256) void cmp_attn_kernel(
    const float* __restrict__ q, const float* __restrict__ ck,
    const float* __restrict__ cv, float* __restrict__ cmp_o,
    unsigned int* __restrict__ blk_mask)
{
    const int s   = blockIdx.x;
    const int kv  = blockIdx.y;
    const int tid = threadIdx.x;

    __shared__ __align__(16) float qs[8][128];
    __shared__ float lt[8][96];
    __shared__ float score[96];
    __shared__ float pooled[24];

    for (int i = tid; i < 8*128; i += 256) {
        int g = i >> 7, d = i & 127;
        qs[g][d] = q[(size_t)(s*HQ + kv*8 + g)*DH + d];
    }
    __syncthreads();

    const int nv = (s >= 31) ? (((s - 31) >> 4) + 1) : 0;

    for (int i = tid; i < 8*TC; i += 256) {
        int g = i / TC, t = i - g*TC;
        const float4* ckr = (const float4*)(ck + (size_t)(t*HKV + kv)*DH);
        const float4* qr  = (const float4*)qs[g];
        float acc = 0.f;
        #pragma unroll 8
        for (int j = 0; j < 32; ++j) {
            float4 a = qr[j], b = ckr[j];
            acc += a.x*b.x + a.y*b.y + a.z*b.z + a.w*b.w;
        }
        lt[g][t] = acc * SCALE;
    }
    __syncthreads();

    const int g = tid >> 5, lane = tid & 31;
    float m = -3.4e38f;
    for (int t = lane; t < nv; t += 32) m = fmaxf(m, lt[g][t]);
    #pragma unroll
    for (int off = 16; off; off >>= 1) m = fmaxf(m, __shfl_xor(m, off, 32));
    float ssum = 0.f;
    for (int t = lane; t < TC; t += 32) {
        float e = (t < nv) ? __expf(lt[g][t] - m) : 0.f;
        lt[g][t] = e;
        ssum += e;
    }
    #pragma unroll
    for (int off = 16; off; off >>= 1) ssum += __shfl_xor(ssum, off, 32);
    const float inv = 1.f / fmaxf(ssum, 1e-9f);
    for (int t = lane; t < TC; t += 32) lt[g][t] *= inv;

    {
        float4 acc = make_float4(0.f, 0.f, 0.f, 0.f);
        for (int t = 0; t < TC; ++t) {
            float p = lt[g][t];
            float4 v4 = *(const float4*)(cv + (size_t)(t*HKV + kv)*DH + lane*4);
            acc.x += p*v4.x; acc.y += p*v4.y; acc.z += p*v4.z; acc.w += p*v4.w;
        }
        *(float4*)(cmp_o + (size_t)(s*HQ + kv*8 + g)*DH + lane*4) = acc;
    }
    __syncthreads();

    if (tid < TC) {
        float sc = 0.f;
        #pragma unroll
        for (int gg = 0; gg < 8; ++gg) sc += lt[gg][tid];
        score[tid] = sc;
    }
    __syncthreads();
    if (tid < 24) {
        float acc = 0.f, cnt = 0.f;
        #pragma unroll
        for (int j = 0; j < 5; ++j) {
            int w = tid*4 + j;
            if (w < TC) { acc += score[w]; cnt += 1.f; }
        }
        pooled[tid] = acc / cnt;
    }
    __syncthreads();
    bool sel = false;
    if (tid < 24) {
        float pvv = pooled[tid];
        int rank = 0;
        #pragma unroll
        for (int j = 0; j < 24; ++j) {
            float pj = pooled[j];
            rank += ((pj > pvv) || (pj == pvv && j < tid)) ? 1 : 0;
        }
        sel = rank < 16;
    }
    unsigned long long b = __ballot(sel);
    if (tid == 0) blk_mask[kv*S_LEN + s] = (unsigned int)(b & 0xFFFFFFull);
}

// ---------------------------------------------------------------- kernel 3
__global__ __launch_bounds__(256, 2) void main_attn_mfma(
    const float* __restrict__ q, const float* __restrict__ kg,
    const float* __restrict__ vg, const float* cmp_o,   // aliases out!
    const unsigned int* __restrict__ blk_mask,
    const float* __restrict__ Wg, const float* __restrict__ bg,
    float* out)
{
    const int t0   = blockIdx.x * TQ;
    const int kv   = blockIdx.y;
    const int z    = blockIdx.z;
    const int tid  = threadIdx.x;
    const int w    = tid >> 6;
    const int lane = tid & 63;
    const int quad = lane >> 4;
    const int l4   = lane & 15;
    const int head = z*4 + w;

    __shared__ __align__(16) f16 Klds[64*136];
    __shared__ __align__(16) f16 Vt[128*72];
    __shared__ __align__(16) f16 Plds[4][16*72];

    f16x8 aq[4];
    {
        const float* qrow = q + ((size_t)(t0 + l4)*HQ + kv*8 + head)*DH;
        #pragma unroll
        for (int ks = 0; ks < 4; ++ks) {
            float4 A = *(const float4*)(qrow + ks*32 + quad*8);
            float4 B = *(const float4*)(qrow + ks*32 + quad*8 + 4);
            aq[ks] = cvt8(A, B);
        }
    }

    int srow[4]; unsigned selm[4];
    #pragma unroll
    for (int r = 0; r < 4; ++r) {
        srow[r] = t0 + quad*4 + r;
        selm[r] = blk_mask[kv*S_LEN + srow[r]];
    }
    unsigned um = 0;
    for (int i = 0; i < TQ; ++i) um |= blk_mask[kv*S_LEN + t0 + i];

    f32x4 o_s[8], o_w[8];
    #pragma unroll
    for (int nf = 0; nf < 8; ++nf) {
        o_s[nf] = (f32x4){0.f,0.f,0.f,0.f};
        o_w[nf] = (f32x4){0.f,0.f,0.f,0.f};
    }
    float m_s[4], l_s[4], m_w[4], l_w[4];
    #pragma unroll
    for (int r = 0; r < 4; ++r) { m_s[r]=-1e30f; l_s[r]=0.f; m_w[r]=-1e30f; l_w[r]=0.f; }

    const int nkb = ((t0 + TQ - 1) >> 6) + 1;
    const int wlo_tile = t0 - WIN + 1;

    for (int kb = 0; kb < nkb; ++kb) {
        const bool any_sel = (um >> kb) & 1u;
        const bool any_win = (kb*64 + 63) >= wlo_tile;
        if (!(any_sel || any_win)) continue;

        __syncthreads();
        #pragma unroll
        for (int i = 0; i < 4; ++i) {
            int idx = i*256 + tid;
            int key = idx >> 4, cg = idx & 15;
            const float* src = kg + (((size_t)(kb*64 + key)*HKV + kv))*DH + cg*8;
            float4 A = *(const float4*)src, B = *(const float4*)(src + 4);
            *(f16x8*)&Klds[key*136 + cg*8] = cvt8(A, B);
        }
        #pragma unroll
        for (int i = 0; i < 4; ++i) {
            int idx = i*256 + tid;
            int d = idx & 127, kg8 = idx >> 7;
            f16x8 h;
            #pragma unroll
            for (int j = 0; j < 8; ++j)
                h[j] = (f16)vg[(((size_t)(kb*64 + kg8*8 + j)*HKV + kv))*DH + d];
            *(f16x8*)&Vt[d*72 + kg8*8] = h;
        }
        __syncthreads();

        f32x4 sc[4];
        #pragma unroll
        for (int nt = 0; nt < 4; ++nt) {
            sc[nt] = (f32x4){0.f,0.f,0.f,0.f};
            #pragma unroll
            for (int ks = 0; ks < 4; ++ks) {
                f16x8 bk = *(const f16x8*)&Klds[(nt*16 + l4)*136 + ks*32 + quad*8];
                sc[nt] = __builtin_amdgcn_mfma_f32_16x16x32_f16(aq[ks], bk, sc[nt], 0, 0, 0);
            }
        }

        const int keyb = kb*64;
        // ================= branch SEL =================
        {
            float rmax[4] = {-1e30f,-1e30f,-1e30f,-1e30f};
            #pragma unroll
            for (int nt = 0; nt < 4; ++nt) {
                int key = keyb + nt*16 + l4;
                #pragma unroll
                for (int r = 0; r < 4; ++r) {
                    bool ok = (key <= srow[r]) && ((selm[r] >> kb) & 1u);
                    rmax[r] = fmaxf(rmax[r], ok ? sc[nt][r]*SCALE : -1e30f);
                }
            }
            float alpha[4];
            #pragma unroll
            for (int r = 0; r < 4; ++r) {
                #pragma unroll
                for (int off = 1; off < 16; off <<= 1)
                    rmax[r] = fmaxf(rmax[r], __shfl_xor(rmax[r], off));
                float nm = fmaxf(m_s[r], rmax[r]);
                alpha[r] = __expf(m_s[r] - nm);
                m_s[r] = nm;
            }
            float rs[4] = {0.f,0.f,0.f,0.f};
            #pragma unroll
            for (int nt = 0; nt < 4; ++nt) {
                int key = keyb + nt*16 + l4;
                #pragma unroll
                for (int r = 0; r < 4; ++r) {
                    bool ok = (key <= srow[r]) && ((selm[r] >> kb) & 1u);
                    float p = ok ? __expf(sc[nt][r]*SCALE - m_s[r]) : 0.f;
                    rs[r] += p;
                    Plds[w][(quad*4 + r)*72 + nt*16 + l4] = (f16)p;
                }
            }
            #pragma unroll
            for (int r = 0; r < 4; ++r) {
                #pragma unroll
                for (int off = 1; off < 16; off <<= 1) rs[r] += __shfl_xor(rs[r], off);
                l_s[r] = l_s[r]*alpha[r] + rs[r];
            }
            #pragma unroll
            for (int nf = 0; nf < 8; ++nf) {
                #pragma unroll
                for (int r = 0; r < 4; ++r) o_s[nf][r] *= alpha[r];
            }
            #pragma unroll
            for (int ks2 = 0; ks2 < 2; ++ks2) {
                f16x8 ap = *(const f16x8*)&Plds[w][l4*72 + ks2*32 + quad*8];
                #pragma unroll
                for (int nf = 0; nf < 8; ++nf) {
                    f16x8 bv = *(const f16x8*)&Vt[(nf*16 + l4)*72 + ks2*32 + quad*8];
                    o_s[nf] = __builtin_amdgcn_mfma_f32_16x16x32_f16(ap, bv, o_s[nf], 0, 0, 0);
                }
            }
        }
        // ================= branch WIN =================
        {
            float rmax[4] = {-1e30f,-1e30f,-1e30f,-1e30f};
            #pragma unroll
            for (int nt = 0; nt < 4; ++nt) {
                int key = keyb + nt*16 + l4;
                #pragma unroll
                for (int r = 0; r < 4; ++r) {
                    bool ok = (key <= srow[r]) && (key > srow[r] - WIN);
                    rmax[r] = fmaxf(rmax[r], ok ? sc[nt][r]*SCALE : -1e30f);
                }
            }
            float alpha[4];
            #pragma unroll
            for (int r = 0; r < 4; ++r) {
                #pragma unroll
                for (int off = 1; off < 16; off <<= 1)
                    rmax[r] = fmaxf(rmax[r], __shfl_xor(rmax[r], off));
                float nm = fmaxf(m_w[r], rmax[r]);
                alpha[r] = __expf(m_w[r] - nm);
                m_w[r] = nm;
            }
            float rs[4] = {0.f,0.f,0.f,0.f};
            #pragma unroll
            for (int nt = 0; nt < 4; ++nt) {
                int key = keyb + nt*16 + l4;
                #pragma unroll
                for (int r = 0; r < 4; ++r) {
                    bool ok = (key <= srow[r]) && (key > srow[r] - WIN);
                    float p = ok ? __expf(sc[nt][r]*SCALE - m_w[r]) : 0.f;
                    rs[r] += p;
                    Plds[w][(quad*4 + r)*72 + nt*16 + l4] = (f16)p;
                }
            }
            #pragma unroll
            for (int r = 0; r < 4; ++r) {
                #pragma unroll
                for (int off = 1; off < 16; off <<= 1) rs[r] += __shfl_xor(rs[r], off);
                l_w[r] = l_w[r]*alpha[r] + rs[r];
            }
            #pragma unroll
            for (int nf = 0; nf < 8; ++nf) {
                #pragma unroll
                for (int r = 0; r < 4; ++r) o_w[nf][r] *= alpha[r];
            }
            #pragma unroll
            for (int ks2 = 0; ks2 < 2; ++ks2) {
                f16x8 ap = *(const f16x8*)&Plds[w][l4*72 + ks2*32 + quad*8];
                #pragma unroll
                for (int nf = 0; nf < 8; ++nf) {
                    f16x8 bv = *(const f16x8*)&Vt[(nf*16 + l4)*72 + ks2*32 + quad*8];
                    o_w[nf] = __builtin_amdgcn_mfma_f32_16x16x32_f16(ap, bv, o_w[nf], 0, 0, 0);
                }
            }
        }
    }

    float inv_s[4], inv_w[4];
    #pragma unroll
    for (int r = 0; r < 4; ++r) {
        inv_s[r] = 1.f / fmaxf(l_s[r], 1e-9f);
        inv_w[r] = 1.f / fmaxf(l_w[r], 1e-9f);
    }
    float gt[4][3];
    #pragma unroll
    for (int r = 0; r < 4; ++r) {
        float p0 = 0.f, p1 = 0.f, p2 = 0.f;
        const float* qrow = q + ((size_t)srow[r]*HQ + kv*8 + head)*DH + l4*8;
        #pragma unroll
        for (int j = 0; j < 8; ++j) {
            float qv = qrow[j];
            int d = l4*8 + j;
            p0 += qv * Wg[d*3 + 0];
            p1 += qv * Wg[d*3 + 1];
            p2 += qv * Wg[d*3 + 2];
        }
        #pragma unroll
        for (int off = 1; off < 16; off <<= 1) {
            p0 += __shfl_xor(p0, off);
            p1 += __shfl_xor(p1, off);
            p2 += __shfl_xor(p2, off);
        }
        gt[r][0] = 1.f/(1.f + __expf(-(p0 + bg[0])));
        gt[r][1] = 1.f/(1.f + __expf(-(p1 + bg[1])));
        gt[r][2] = 1.f/(1.f + __expf(-(p2 + bg[2])));
    }
    #pragma unroll
    for (int nf = 0; nf < 8; ++nf) {
        int d = nf*16 + l4;
        #pragma unroll
        for (int r = 0; r < 4; ++r) {
            size_t oi = ((size_t)srow[r]*HQ + kv*8 + head)*DH + d;
            float cm = cmp_o[oi];
            out[oi] = gt[r][0]*o_s[nf][r]*inv_s[r]
                    + gt[r][1]*o_w[nf][r]*inv_w[r]
                    + gt[r][2]*cm;
        }
    }
}

// ---------------------------------------------------------------- launcher
extern "C" void kernel_launch(void* const* d_in, const int* in_sizes, int n_in,
                              void* d_out, int out_size, void* d_ws, size_t ws_size,
                              hipStream_t stream) {
    const float* q   = (const float*)d_in[0];
    const float* k   = (const float*)d_in[1];
    const float* v   = (const float*)d_in[2];
    const float* Wk  = (const float*)d_in[3];
    const float* bk  = (const float*)d_in[4];
    const float* Wv  = (const float*)d_in[5];
    const float* bv  = (const float*)d_in[6];
    const float* pek = (const float*)d_in[7];
    const float* pev = (const float*)d_in[8];
    const float* Wg  = (const float*)d_in[9];
    const float* bg  = (const float*)d_in[10];
    float* out = (float*)d_out;

    char* ws = (char*)d_ws;
    float* ck = (float*)ws;
    float* cv = (float*)(ws + 98304);
    unsigned int* blk_mask = (unsigned int*)(ws + 196608);
    float* cmp_o = out;

    compress_init_kernel<<<dim3(190), 256, 0, stream>>>(bk, bv, ck, cv);
    compress_partial_kernel<<<dim3(19, 4, 8), 256, 0, stream>>>(
        k, v, Wk, Wv, pek, pev, ck, cv);
    cmp_attn_kernel<<<dim3(S_LEN, HKV), 256, 0, stream>>>(
        q, ck, cv, cmp_o, blk_mask);
    main_attn_mfma<<<dim3(S_LEN/TQ, HKV, 2), 256, 0, stream>>>(
        q, k, v, cmp_o, blk_mask, Wg, bg, out);
}

// Round 4
// 306.774 us; speedup vs baseline: 2.7707x; 1.4373x over previous
//
#include <hip/hip_runtime.h>

// NSA attention. K0: init ck/cv with bias. K1: K-split compress (fp32, atomics).
// K2: cmp attention + topk (fp32 selection path, f16 cv for PV).
// K3: query-tiled MFMA flash attention, coalesced V + LDS transpose.

#define S_LEN 1536
#define HQ    16
#define HKV   2
#define DH    128
#define TC    95
#define WIN   512
#define TQ    16
#define SCALE 0.08838834764831845f   // 1/sqrt(128)

typedef _Float16 f16;
typedef f16   f16x4 __attribute__((ext_vector_type(4)));
typedef f16   f16x8 __attribute__((ext_vector_type(8)));
typedef float f32x4 __attribute__((ext_vector_type(4)));

__device__ inline f16x8 cvt8(float4 A, float4 B) {
    f16x8 h;
    h[0]=(f16)A.x; h[1]=(f16)A.y; h[2]=(f16)A.z; h[3]=(f16)A.w;
    h[4]=(f16)B.x; h[5]=(f16)B.y; h[6]=(f16)B.z; h[7]=(f16)B.w;
    return h;
}

// ---------------------------------------------------------------- kernel 0
__global__ __launch_bounds__(256) void compress_init_kernel(
    const float* __restrict__ bk, const float* __restrict__ bv,
    float* __restrict__ ck, float* __restrict__ cv)
{
    int i = blockIdx.x * 256 + threadIdx.x;       // 190 blocks * 256 = 48640
    int which = i >= TC*HKV*DH;
    int j = i - which*(TC*HKV*DH);
    int d = j & 127;
    (which ? cv : ck)[j] = (which ? bv : bk)[d];
}

// ---------------------------------------------------------------- kernel 1
__global__ __launch_bounds__(256) void compress_partial_kernel(
    const float* __restrict__ kin, const float* __restrict__ vin,
    const float* __restrict__ Wk,  const float* __restrict__ Wv,
    const float* __restrict__ pek, const float* __restrict__ pev,
    float* __restrict__ ck, float* __restrict__ cv)
{
    const int t0    = blockIdx.x * 5;
    const int kv    = blockIdx.y >> 1;
    const int which = blockIdx.y & 1;
    const int kc    = blockIdx.z;
    const float* __restrict__ x  = which ? vin : kin;
    const float* __restrict__ W  = which ? Wv  : Wk;
    const float* __restrict__ pe = which ? pev : pek;
    float* __restrict__ outp     = which ? cv  : ck;
    const int tid = threadIdx.x;
    const int hh  = tid >> 7;
    const int d   = tid & 127;

    __shared__ float xs[2][5][128];
    __shared__ float racc[5][128];
    float acc[5] = {0.f, 0.f, 0.f, 0.f, 0.f};

    #pragma unroll
    for (int il = 0; il < 2; ++il) {
        const int l = kc*4 + hh*2 + il;
        float p = pe[l*DH + d];
        #pragma unroll
        for (int tt = 0; tt < 5; ++tt) {
            int row = (t0 + tt)*16 + l;
            xs[hh][tt][d] = x[(row*HKV + kv)*DH + d] + p;
        }
        __syncthreads();
        const float* wcol = W + l*DH*DH + d;
        #pragma unroll 4
        for (int dd = 0; dd < 128; ++dd) {
            float wv = wcol[dd*DH];
            #pragma unroll
            for (int tt = 0; tt < 5; ++tt) acc[tt] += xs[hh][tt][dd] * wv;
        }
        __syncthreads();
    }
    if (hh == 1) {
        #pragma unroll
        for (int tt = 0; tt < 5; ++tt) racc[tt][d] = acc[tt];
    }
    __syncthreads();
    if (hh == 0) {
        #pragma unroll
        for (int tt = 0; tt < 5; ++tt)
            atomicAdd(&outp[((t0 + tt)*HKV + kv)*DH + d], acc[tt] + racc[tt][d]);
    }
}

// ---------------------------------------------------------------- kernel 2
// fp32 logits/softmax/score/topk (selection must be fp32-exact vs ties);
// 8-lane-split dot for latency; cv staged to LDS as f16 for the PV loop.
__global__ __launch_bounds__(256) void cmp_attn_kernel(
    const float* __restrict__ q, const float* __restrict__ ck,
    const float* __restrict__ cv, float* __restrict__ cmp_o,
    unsigned int* __restrict__ blk_mask)
{
    const int s   = blockIdx.x;
    const int kv  = blockIdx.y;
    const int tid = threadIdx.x;

    __shared__ __align__(16) float qs[8*132];   // stride 132: spread banks
    __shared__ __align__(16) f16  cvs[TC*132];  // f16 cv tile
    __shared__ float lt[8][96];
    __shared__ float score[96];
    __shared__ float pooled[24];

    for (int i = tid; i < 8*128; i += 256) {
        int g = i >> 7, d = i & 127;
        qs[g*132 + d] = q[(size_t)(s*HQ + kv*8 + g)*DH + d];
    }
    for (int i = tid; i < TC*32; i += 256) {
        int t = i >> 5, c = i & 31;
        float4 a = *(const float4*)(cv + (size_t)(t*HKV + kv)*DH + c*4);
        f16x4 h; h[0]=(f16)a.x; h[1]=(f16)a.y; h[2]=(f16)a.z; h[3]=(f16)a.w;
        *(f16x4*)&cvs[t*132 + c*4] = h;
    }
    __syncthreads();

    const int nv = (s >= 31) ? (((s - 31) >> 4) + 1) : 0;

    // logits: 760 tasks (g,t), 8 lanes each (16 MACs + shuffle reduce)
    const int sub = tid & 7;
    for (int task = tid >> 3; task < 8*TC; task += 32) {
        int g = task / TC, t = task - g*TC;
        const float4* ckr = (const float4*)(ck + (size_t)(t*HKV + kv)*DH) + sub*4;
        const float*  qp  = qs + g*132 + sub*16;
        float acc = 0.f;
        #pragma unroll
        for (int j = 0; j < 4; ++j) {
            float4 b = ckr[j];
            const float* a = qp + j*4;
            acc += a[0]*b.x + a[1]*b.y + a[2]*b.z + a[3]*b.w;
        }
        #pragma unroll
        for (int off = 4; off; off >>= 1) acc += __shfl_xor(acc, off, 8);
        if (sub == 0) lt[g][t] = acc * SCALE;
    }
    __syncthreads();

    // masked softmax per head; 32 lanes per head (fp32, matches R1 semantics)
    const int g = tid >> 5, lane = tid & 31;
    float m = -3.4e38f;
    for (int t = lane; t < nv; t += 32) m = fmaxf(m, lt[g][t]);
    #pragma unroll
    for (int off = 16; off; off >>= 1) m = fmaxf(m, __shfl_xor(m, off, 32));
    float ssum = 0.f;
    for (int t = lane; t < TC; t += 32) {
        float e = (t < nv) ? __expf(lt[g][t] - m) : 0.f;
        lt[g][t] = e;
        ssum += e;
    }
    #pragma unroll
    for (int off = 16; off; off >>= 1) ssum += __shfl_xor(ssum, off, 32);
    const float inv = 1.f / fmaxf(ssum, 1e-9f);
    for (int t = lane; t < TC; t += 32) lt[g][t] *= inv;

    // PV from LDS f16 cv
    {
        float4 acc = make_float4(0.f, 0.f, 0.f, 0.f);
        #pragma unroll 5
        for (int t = 0; t < TC; ++t) {
            float p = lt[g][t];
            f16x4 h = *(const f16x4*)&cvs[t*132 + lane*4];
            acc.x += p*(float)h[0]; acc.y += p*(float)h[1];
            acc.z += p*(float)h[2]; acc.w += p*(float)h[3];
        }
        *(float4*)(cmp_o + (size_t)(s*HQ + kv*8 + g)*DH + lane*4) = acc;
    }
    __syncthreads();

    if (tid < TC) {
        float sc = 0.f;
        #pragma unroll
        for (int gg = 0; gg < 8; ++gg) sc += lt[gg][tid];
        score[tid] = sc;
    }
    __syncthreads();
    if (tid < 24) {
        float acc = 0.f, cnt = 0.f;
        #pragma unroll
        for (int j = 0; j < 5; ++j) {
            int w = tid*4 + j;
            if (w < TC) { acc += score[w]; cnt += 1.f; }
        }
        pooled[tid] = acc / cnt;
    }
    __syncthreads();
    bool sel = false;
    if (tid < 24) {
        float pvv = pooled[tid];
        int rank = 0;
        #pragma unroll
        for (int j = 0; j < 24; ++j) {
            float pj = pooled[j];
            rank += ((pj > pvv) || (pj == pvv && j < tid)) ? 1 : 0;
        }
        sel = rank < 16;
    }
    unsigned long long b = __ballot(sel);
    if (tid == 0) blk_mask[kv*S_LEN + s] = (unsigned int)(b & 0xFFFFFFull);
}

// ---------------------------------------------------------------- kernel 3
__global__ __launch_bounds__(256, 2) void main_attn_mfma(
    const float* __restrict__ q, const float* __restrict__ kg,
    const float* __restrict__ vg, const float* cmp_o,   // aliases out!
    const unsigned int* __restrict__ blk_mask,
    const float* __restrict__ Wg, const float* __restrict__ bg,
    float* out)
{
    // big tiles first: they dominate the makespan
    const int t0   = (S_LEN/TQ - 1 - blockIdx.x) * TQ;
    const int kv   = blockIdx.y;
    const int z    = blockIdx.z;
    const int tid  = threadIdx.x;
    const int w    = tid >> 6;
    const int lane = tid & 63;
    const int quad = lane >> 4;
    const int l4   = lane & 15;
    const int head = z*4 + w;

    __shared__ __align__(16) f16 Klds[64*136];   // 17408 B
    __shared__ __align__(16) f16 Vrow[64*136];   // 17408 B (coalesced V rows)
    __shared__ __align__(16) f16 Vt[128*72];     // 18432 B (transposed)
    __shared__ __align__(16) f16 Plds[4][16*72]; //  9216 B

    f16x8 aq[4];
    {
        const float* qrow = q + ((size_t)(t0 + l4)*HQ + kv*8 + head)*DH;
        #pragma unroll
        for (int ks = 0; ks < 4; ++ks) {
            float4 A = *(const float4*)(qrow + ks*32 + quad*8);
            float4 B = *(const float4*)(qrow + ks*32 + quad*8 + 4);
            aq[ks] = cvt8(A, B);
        }
    }

    int srow[4]; unsigned selm[4];
    #pragma unroll
    for (int r = 0; r < 4; ++r) {
        srow[r] = t0 + quad*4 + r;
        selm[r] = blk_mask[kv*S_LEN + srow[r]];
    }
    unsigned um = 0;
    for (int i = 0; i < TQ; ++i) um |= blk_mask[kv*S_LEN + t0 + i];

    f32x4 o_s[8], o_w[8];
    #pragma unroll
    for (int nf = 0; nf < 8; ++nf) {
        o_s[nf] = (f32x4){0.f,0.f,0.f,0.f};
        o_w[nf] = (f32x4){0.f,0.f,0.f,0.f};
    }
    float m_s[4], l_s[4], m_w[4], l_w[4];
    #pragma unroll
    for (int r = 0; r < 4; ++r) { m_s[r]=-1e30f; l_s[r]=0.f; m_w[r]=-1e30f; l_w[r]=0.f; }

    const int nkb = ((t0 + TQ - 1) >> 6) + 1;
    const int wlo_tile = t0 - WIN + 1;

    for (int kb = 0; kb < nkb; ++kb) {
        const bool any_sel = (um >> kb) & 1u;
        const bool any_win = (kb*64 + 63) >= wlo_tile;
        if (!(any_sel || any_win)) continue;   // block-uniform

        __syncthreads();
        // ---- stage K + V rows, both coalesced float4
        #pragma unroll
        for (int i = 0; i < 4; ++i) {
            int idx = i*256 + tid;
            int key = idx >> 4, cg = idx & 15;
            const float* srcK = kg + (((size_t)(kb*64 + key)*HKV + kv))*DH + cg*8;
            const float* srcV = vg + (((size_t)(kb*64 + key)*HKV + kv))*DH + cg*8;
            float4 A = *(const float4*)srcK, B = *(const float4*)(srcK + 4);
            *(f16x8*)&Klds[key*136 + cg*8] = cvt8(A, B);
            float4 C = *(const float4*)srcV, D = *(const float4*)(srcV + 4);
            *(f16x8*)&Vrow[key*136 + cg*8] = cvt8(C, D);
        }
        __syncthreads();
        // ---- LDS transpose Vrow[key][d] -> Vt[d][key] (broadcast-pair reads)
        #pragma unroll
        for (int i = 0; i < 4; ++i) {
            int idx = i*256 + tid;
            int d = idx & 127, kg8 = idx >> 7;
            f16x8 h;
            #pragma unroll
            for (int j = 0; j < 8; ++j) h[j] = Vrow[(kg8*8 + j)*136 + d];
            *(f16x8*)&Vt[d*72 + kg8*8] = h;
        }
        __syncthreads();

        // ---- S = Q K^T
        f32x4 sc[4];
        #pragma unroll
        for (int nt = 0; nt < 4; ++nt) {
            sc[nt] = (f32x4){0.f,0.f,0.f,0.f};
            #pragma unroll
            for (int ks = 0; ks < 4; ++ks) {
                f16x8 bk = *(const f16x8*)&Klds[(nt*16 + l4)*136 + ks*32 + quad*8];
                sc[nt] = __builtin_amdgcn_mfma_f32_16x16x32_f16(aq[ks], bk, sc[nt], 0, 0, 0);
            }
        }

        const int keyb = kb*64;
        // ================= branch SEL =================
        if (any_sel) {
            float rmax[4] = {-1e30f,-1e30f,-1e30f,-1e30f};
            #pragma unroll
            for (int nt = 0; nt < 4; ++nt) {
                int key = keyb + nt*16 + l4;
                #pragma unroll
                for (int r = 0; r < 4; ++r) {
                    bool ok = (key <= srow[r]) && ((selm[r] >> kb) & 1u);
                    rmax[r] = fmaxf(rmax[r], ok ? sc[nt][r]*SCALE : -1e30f);
                }
            }
            float alpha[4];
            #pragma unroll
            for (int r = 0; r < 4; ++r) {
                #pragma unroll
                for (int off = 1; off < 16; off <<= 1)
                    rmax[r] = fmaxf(rmax[r], __shfl_xor(rmax[r], off));
                float nm = fmaxf(m_s[r], rmax[r]);
                alpha[r] = __expf(m_s[r] - nm);
                m_s[r] = nm;
            }
            float rs[4] = {0.f,0.f,0.f,0.f};
            #pragma unroll
            for (int nt = 0; nt < 4; ++nt) {
                int key = keyb + nt*16 + l4;
                #pragma unroll
                for (int r = 0; r < 4; ++r) {
                    bool ok = (key <= srow[r]) && ((selm[r] >> kb) & 1u);
                    float p = ok ? __expf(sc[nt][r]*SCALE - m_s[r]) : 0.f;
                    rs[r] += p;
                    Plds[w][(quad*4 + r)*72 + nt*16 + l4] = (f16)p;
                }
            }
            #pragma unroll
            for (int r = 0; r < 4; ++r) {
                #pragma unroll
                for (int off = 1; off < 16; off <<= 1) rs[r] += __shfl_xor(rs[r], off);
                l_s[r] = l_s[r]*alpha[r] + rs[r];
            }
            #pragma unroll
            for (int nf = 0; nf < 8; ++nf) {
                #pragma unroll
                for (int r = 0; r < 4; ++r) o_s[nf][r] *= alpha[r];
            }
            #pragma unroll
            for (int ks2 = 0; ks2 < 2; ++ks2) {
                f16x8 ap = *(const f16x8*)&Plds[w][l4*72 + ks2*32 + quad*8];
                #pragma unroll
                for (int nf = 0; nf < 8; ++nf) {
                    f16x8 bv = *(const f16x8*)&Vt[(nf*16 + l4)*72 + ks2*32 + quad*8];
                    o_s[nf] = __builtin_amdgcn_mfma_f32_16x16x32_f16(ap, bv, o_s[nf], 0, 0, 0);
                }
            }
        }
        // ================= branch WIN =================
        if (any_win) {
            float rmax[4] = {-1e30f,-1e30f,-1e30f,-1e30f};
            #pragma unroll
            for (int nt = 0; nt < 4; ++nt) {
                int key = keyb + nt*16 + l4;
                #pragma unroll
                for (int r = 0; r < 4; ++r) {
                    bool ok = (key <= srow[r]) && (key > srow[r] - WIN);
                    rmax[r] = fmaxf(rmax[r], ok ? sc[nt][r]*SCALE : -1e30f);
                }
            }
            float alpha[4];
            #pragma unroll
            for (int r = 0; r < 4; ++r) {
                #pragma unroll
                for (int off = 1; off < 16; off <<= 1)
                    rmax[r] = fmaxf(rmax[r], __shfl_xor(rmax[r], off));
                float nm = fmaxf(m_w[r], rmax[r]);
                alpha[r] = __expf(m_w[r] - nm);
                m_w[r] = nm;
            }
            float rs[4] = {0.f,0.f,0.f,0.f};
            #pragma unroll
            for (int nt = 0; nt < 4; ++nt) {
                int key = keyb + nt*16 + l4;
                #pragma unroll
                for (int r = 0; r < 4; ++r) {
                    bool ok = (key <= srow[r]) && (key > srow[r] - WIN);
                    float p = ok ? __expf(sc[nt][r]*SCALE - m_w[r]) : 0.f;
                    rs[r] += p;
                    Plds[w][(quad*4 + r)*72 + nt*16 + l4] = (f16)p;
                }
            }
            #pragma unroll
            for (int r = 0; r < 4; ++r) {
                #pragma unroll
                for (int off = 1; off < 16; off <<= 1) rs[r] += __shfl_xor(rs[r], off);
                l_w[r] = l_w[r]*alpha[r] + rs[r];
            }
            #pragma unroll
            for (int nf = 0; nf < 8; ++nf) {
                #pragma unroll
                for (int r = 0; r < 4; ++r) o_w[nf][r] *= alpha[r];
            }
            #pragma unroll
            for (int ks2 = 0; ks2 < 2; ++ks2) {
                f16x8 ap = *(const f16x8*)&Plds[w][l4*72 + ks2*32 + quad*8];
                #pragma unroll
                for (int nf = 0; nf < 8; ++nf) {
                    f16x8 bv = *(const f16x8*)&Vt[(nf*16 + l4)*72 + ks2*32 + quad*8];
                    o_w[nf] = __builtin_amdgcn_mfma_f32_16x16x32_f16(ap, bv, o_w[nf], 0, 0, 0);
                }
            }
        }
    }

    float inv_s[4], inv_w[4];
    #pragma unroll
    for (int r = 0; r < 4; ++r) {
        inv_s[r] = 1.f / fmaxf(l_s[r], 1e-9f);
        inv_w[r] = 1.f / fmaxf(l_w[r], 1e-9f);
    }
    float gt[4][3];
    #pragma unroll
    for (int r = 0; r < 4; ++r) {
        float p0 = 0.f, p1 = 0.f, p2 = 0.f;
        const float* qrow = q + ((size_t)srow[r]*HQ + kv*8 + head)*DH + l4*8;
        #pragma unroll
        for (int j = 0; j < 8; ++j) {
            float qv = qrow[j];
            int d = l4*8 + j;
            p0 += qv * Wg[d*3 + 0];
            p1 += qv * Wg[d*3 + 1];
            p2 += qv * Wg[d*3 + 2];
        }
        #pragma unroll
        for (int off = 1; off < 16; off <<= 1) {
            p0 += __shfl_xor(p0, off);
            p1 += __shfl_xor(p1, off);
            p2 += __shfl_xor(p2, off);
        }
        gt[r][0] = 1.f/(1.f + __expf(-(p0 + bg[0])));
        gt[r][1] = 1.f/(1.f + __expf(-(p1 + bg[1])));
        gt[r][2] = 1.f/(1.f + __expf(-(p2 + bg[2])));
    }
    #pragma unroll
    for (int nf = 0; nf < 8; ++nf) {
        int d = nf*16 + l4;
        #pragma unroll
        for (int r = 0; r < 4; ++r) {
            size_t oi = ((size_t)srow[r]*HQ + kv*8 + head)*DH + d;
            float cm = cmp_o[oi];
            out[oi] = gt[r][0]*o_s[nf][r]*inv_s[r]
                    + gt[r][1]*o_w[nf][r]*inv_w[r]
                    + gt[r][2]*cm;
        }
    }
}

// ---------------------------------------------------------------- launcher
extern "C" void kernel_launch(void* const* d_in, const int* in_sizes, int n_in,
                              void* d_out, int out_size, void* d_ws, size_t ws_size,
                              hipStream_t stream) {
    const float* q   = (const float*)d_in[0];
    const float* k   = (const float*)d_in[1];
    const float* v   = (const float*)d_in[2];
    const float* Wk  = (const float*)d_in[3];
    const float* bk  = (const float*)d_in[4];
    const float* Wv  = (const float*)d_in[5];
    const float* bv  = (const float*)d_in[6];
    const float* pek = (const float*)d_in[7];
    const float* pev = (const float*)d_in[8];
    const float* Wg  = (const float*)d_in[9];
    const float* bg  = (const float*)d_in[10];
    float* out = (float*)d_out;

    char* ws = (char*)d_ws;
    float* ck = (float*)ws;
    float* cv = (float*)(ws + 98304);
    unsigned int* blk_mask = (unsigned int*)(ws + 196608);
    float* cmp_o = out;

    compress_init_kernel<<<dim3(190), 256, 0, stream>>>(bk, bv, ck, cv);
    compress_partial_kernel<<<dim3(19, 4, 8), 256, 0, stream>>>(
        k, v, Wk, Wv, pek, pev, ck, cv);
    cmp_attn_kernel<<<dim3(S_LEN, HKV), 256, 0, stream>>>(
        q, ck, cv, cmp_o, blk_mask);
    main_attn_mfma<<<dim3(S_LEN/TQ, HKV, 2), 256, 0, stream>>>(
        q, k, v, cmp_o, blk_mask, Wg, bg, out);
}